// Round 13
// baseline (179.109 us; speedup 1.0000x reference)
//
#include <hip/hip_runtime.h>
#include <cstdint>
#include <cstddef>

#define NB 4
#define TS 2048
#define DM 512
#define HN 8
#define HD 64

typedef __attribute__((ext_vector_type(8))) short bf16x8;
typedef __attribute__((ext_vector_type(16))) float f32x16;
typedef __attribute__((ext_vector_type(4))) float f32x4;
typedef __attribute__((ext_vector_type(4))) short short4v;
typedef __attribute__((ext_vector_type(4))) unsigned u32x4;

static __device__ __forceinline__ short f2bf(float f) {
  unsigned u = __float_as_uint(f);
  unsigned r = (u + 0x7fffu + ((u >> 16) & 1u)) >> 16;  // RNE
  return (short)r;
}

static __device__ __forceinline__ float bf2f(short s) {
  return __uint_as_float(((unsigned)(unsigned short)s) << 16);
}

static __device__ __forceinline__ unsigned cvtpk(float lo, float hi) {
  unsigned r;
  asm("v_cvt_pk_bf16_f32 %0, %1, %2" : "=v"(r) : "v"(lo), "v"(hi));
  return r;
}

// x' = {x.lanes0-31, y.lanes0-31}; y' = {x.lanes32-63, y.lanes32-63}
static __device__ __forceinline__ void plane32swap(unsigned& x, unsigned& y) {
  asm volatile("v_permlane32_swap_b32 %0, %1" : "+v"(x), "+v"(y));
}

static __device__ __forceinline__ void gload16(const void* g, void* l) {
  __builtin_amdgcn_global_load_lds(
      (const __attribute__((address_space(1))) void*)g,
      (__attribute__((address_space(3))) void*)l, 16, 0, 0);
}

#define WAIT_VM(N) asm volatile("s_waitcnt vmcnt(" #N ")" ::: "memory")
#define BAR() __builtin_amdgcn_s_barrier()

#define MFMA16(a, b, c) __builtin_amdgcn_mfma_f32_16x16x32_bf16((a), (b), (c), 0, 0, 0)
#define MFMA32(a, b, c) __builtin_amdgcn_mfma_f32_32x32x16_bf16((a), (b), (c), 0, 0, 0)

// ---- fused cast: Q (fp32->bf16) + 3 weights; Wk gets +1.0 on the diagonal ----
__global__ __launch_bounds__(256) void cast_all(const float* __restrict__ Q,
                                                const float* __restrict__ Wk,
                                                const float* __restrict__ Wv,
                                                const float* __restrict__ Wo,
                                                short* __restrict__ Qb,
                                                short* __restrict__ Wb) {
  int i = blockIdx.x * 256 + threadIdx.x;
  const int Q4 = (NB * TS * DM) / 4;  // 1048576
  const float* src;
  short* dst;
  int off;
  int which = -1;
  if (i < Q4) {
    src = Q; dst = Qb; off = i;
  } else {
    int j = i - Q4;
    which = j >> 16;  // WE/4 = 65536
    off = j & 65535;
    src = which == 0 ? Wk : (which == 1 ? Wv : Wo);
    dst = Wb + ((size_t)which << 18);  // WE = 262144
  }
  float4 v = reinterpret_cast<const float4*>(src)[off];
  if (which == 0) {
    int e0 = off * 4;
    int row = e0 >> 9;
    int col0 = e0 & 511;
    if (row >= col0 && row < col0 + 4) {
      int c = row - col0;
      if (c == 0) v.x += 1.0f;
      else if (c == 1) v.y += 1.0f;
      else if (c == 2) v.z += 1.0f;
      else v.w += 1.0f;
    }
  }
  short4v o;
  o.x = f2bf(v.x);
  o.y = f2bf(v.y);
  o.z = f2bf(v.z);
  o.w = f2bf(v.w);
  reinterpret_cast<short4v*>(dst)[off] = o;
}

// ---- fused K+V projection writing FRAGMENT-PACKED outputs (R11 config) ----
// Kpack/Vpack unit: [(nh*32 + t)*8 + blk][lane 0..63][8 shorts]   (1KB blocks)
//   K: blk = H*4 + ks, lane = (k&31) + 32*((dd>>3)&1), j = dd&7   (H = k-half)
//   V: blk = D*4 + ks, lane = (dd&31) + 32*((k>>3)&1), j = k&7    (D = d-half)
__global__ __launch_bounds__(256) void gemm_kv(const short* __restrict__ Qb,
                                               const short* __restrict__ Wkb,
                                               const short* __restrict__ Wvb,
                                               short* __restrict__ KP,
                                               short* __restrict__ VP) {
  __shared__ alignas(16) short lA[2][128 * 32];  // Q tile
  __shared__ alignas(16) short lK[2][64 * 32];   // Wk tile
  __shared__ alignas(16) short lV[2][64 * 32];   // Wv tile
  const int row0 = blockIdx.x * 128;  // seq
  const int col0d = blockIdx.y * 64;  // d
  const int tid = threadIdx.x;
  const int lane = tid & 63;
  const int wave = tid >> 6;
  const int wr = wave >> 1, wc = wave & 1;
  const int fr = lane & 15, fk = (lane >> 4) * 8;
  const int g = lane >> 4;

  f32x4 kacc[2][4], vacc[4][2];
  const f32x4 z4 = {0.f, 0.f, 0.f, 0.f};
#pragma unroll
  for (int m = 0; m < 4; ++m)
#pragma unroll
    for (int nn = 0; nn < 2; ++nn) {
      kacc[nn][m] = z4;
      vacc[m][nn] = z4;
    }

  const int sr = tid >> 2;        // 0..63
  const int sc8 = (tid & 3) * 8;  // shorts

#define GSTAGE(buf, kt)                                                 \
  do {                                                                  \
    gload16(&Qb[(size_t)(row0 + sr) * DM + (kt) + sc8],                 \
            (char*)&lA[(buf)][0] + (size_t)tid * 16);                   \
    gload16(&Qb[(size_t)(row0 + 64 + sr) * DM + (kt) + sc8],            \
            (char*)&lA[(buf)][0] + 4096 + (size_t)tid * 16);            \
    gload16(&Wkb[(size_t)(col0d + sr) * DM + (kt) + sc8],               \
            (char*)&lK[(buf)][0] + (size_t)tid * 16);                   \
    gload16(&Wvb[(size_t)(col0d + sr) * DM + (kt) + sc8],               \
            (char*)&lV[(buf)][0] + (size_t)tid * 16);                   \
  } while (0)

  GSTAGE(0, 0);
  __syncthreads();
  int cur = 0;
  for (int kt = 0; kt < 16; ++kt) {
    if (kt < 15) GSTAGE(cur ^ 1, (kt + 1) * 32);
    bf16x8 af[4], wk[2], wv[2];
#pragma unroll
    for (int m = 0; m < 4; ++m)
      af[m] = *reinterpret_cast<const bf16x8*>(&lA[cur][(wr * 64 + m * 16 + fr) * 32 + fk]);
#pragma unroll
    for (int nn = 0; nn < 2; ++nn) {
      wk[nn] = *reinterpret_cast<const bf16x8*>(&lK[cur][(wc * 32 + nn * 16 + fr) * 32 + fk]);
      wv[nn] = *reinterpret_cast<const bf16x8*>(&lV[cur][(wc * 32 + nn * 16 + fr) * 32 + fk]);
    }
    __builtin_amdgcn_s_setprio(1);
#pragma unroll
    for (int m = 0; m < 4; ++m)
#pragma unroll
      for (int nn = 0; nn < 2; ++nn) {
        kacc[nn][m] = MFMA16(wk[nn], af[m], kacc[nn][m]);  // C[d][seq]
        vacc[m][nn] = MFMA16(af[m], wv[nn], vacc[m][nn]);  // C[seq][d]
      }
    __builtin_amdgcn_s_setprio(0);
    __syncthreads();
    cur ^= 1;
  }
#undef GSTAGE

  // K epilogue (C rows = d, cols = seq)
#pragma unroll
  for (int nn = 0; nn < 2; ++nn) {
#pragma unroll
    for (int m = 0; m < 4; ++m) {
      int d = col0d + wc * 32 + nn * 16 + g * 4;
      int kseq = row0 + wr * 64 + m * 16 + fr;
      int h = d >> 6, dd = d & 63;
      int n = kseq >> 11, kk = kseq & (TS - 1);
      int t = kk >> 6, H = (kk >> 5) & 1;
      int ks = (dd >> 4) & 3, hfd = (dd >> 3) & 1, jb = dd & 7;
      int slot = (kk & 31) + 32 * hfd;
      short4v pk;
#pragma unroll
      for (int i = 0; i < 4; ++i) pk[i] = f2bf(kacc[nn][m][i]);
      size_t addr = ((((size_t)(n * HN + h) * 32 + t) * 8 + H * 4 + ks) * 64 + slot) * 8 + jb;
      *reinterpret_cast<short4v*>(&KP[addr]) = pk;
    }
  }
  // V epilogue (C rows = seq, cols = d)
#pragma unroll
  for (int m = 0; m < 4; ++m) {
#pragma unroll
    for (int nn = 0; nn < 2; ++nn) {
      int kseq = row0 + wr * 64 + m * 16 + g * 4;
      int d = col0d + wc * 32 + nn * 16 + fr;
      int h = d >> 6, dd = d & 63;
      int n = kseq >> 11, kk = kseq & (TS - 1);
      int t = kk >> 6, hfk = (kk >> 3) & 1, jb = kk & 7;
      int ksV = (kk >> 4) & 3, D = (dd >> 5) & 1;
      int slot = (dd & 31) + 32 * hfk;
      short4v pv;
#pragma unroll
      for (int i = 0; i < 4; ++i) pv[i] = f2bf(vacc[m][nn][i]);
      size_t addr = ((((size_t)(n * HN + h) * 32 + t) * 8 + D * 4 + ksV) * 64 + slot) * 8 + jb;
      *reinterpret_cast<short4v*>(&VP[addr]) = pv;
    }
  }
}

// ---- O projection GEMM: 128x64 tile, BK=32, dbuf, fp32 out (R11 config) ----
__global__ __launch_bounds__(256) void gemm_o(const short* __restrict__ A,
                                              const short* __restrict__ W,
                                              float* __restrict__ out0) {
  __shared__ alignas(16) short lA[2][128 * 32];
  __shared__ alignas(16) short lB[2][64 * 32];
  const int row0 = blockIdx.x * 128;
  const int col0 = blockIdx.y * 64;
  const int tid = threadIdx.x;
  const int lane = tid & 63;
  const int wave = tid >> 6;
  const int wr = wave >> 1, wc = wave & 1;
  const int fr = lane & 15, fk = (lane >> 4) * 8;

  f32x4 acc[4][2];
  const f32x4 z4 = {0.f, 0.f, 0.f, 0.f};
#pragma unroll
  for (int m = 0; m < 4; ++m)
#pragma unroll
    for (int nn = 0; nn < 2; ++nn) acc[m][nn] = z4;

  const int sr = tid >> 2;
  const int sc8 = (tid & 3) * 8;

#define GSTAGE(buf, kt)                                                \
  do {                                                                 \
    gload16(&A[(size_t)(row0 + sr) * DM + (kt) + sc8],                 \
            (char*)&lA[(buf)][0] + (size_t)tid * 16);                  \
    gload16(&A[(size_t)(row0 + 64 + sr) * DM + (kt) + sc8],            \
            (char*)&lA[(buf)][0] + 4096 + (size_t)tid * 16);           \
    gload16(&W[(size_t)(col0 + sr) * DM + (kt) + sc8],                 \
            (char*)&lB[(buf)][0] + (size_t)tid * 16);                  \
  } while (0)

  GSTAGE(0, 0);
  __syncthreads();
  int cur = 0;
  for (int kt = 0; kt < 16; ++kt) {
    if (kt < 15) GSTAGE(cur ^ 1, (kt + 1) * 32);
    bf16x8 af[4], bfr[2];
#pragma unroll
    for (int m = 0; m < 4; ++m)
      af[m] = *reinterpret_cast<const bf16x8*>(&lA[cur][(wr * 64 + m * 16 + fr) * 32 + fk]);
#pragma unroll
    for (int nn = 0; nn < 2; ++nn)
      bfr[nn] = *reinterpret_cast<const bf16x8*>(&lB[cur][(wc * 32 + nn * 16 + fr) * 32 + fk]);
    __builtin_amdgcn_s_setprio(1);
#pragma unroll
    for (int m = 0; m < 4; ++m)
#pragma unroll
      for (int nn = 0; nn < 2; ++nn) acc[m][nn] = MFMA16(af[m], bfr[nn], acc[m][nn]);
    __builtin_amdgcn_s_setprio(0);
    __syncthreads();
    cur ^= 1;
  }
#undef GSTAGE

#pragma unroll
  for (int m = 0; m < 4; ++m)
#pragma unroll
    for (int nn = 0; nn < 2; ++nn)
#pragma unroll
      for (int i = 0; i < 4; ++i) {
        int gr = row0 + wr * 64 + m * 16 + (lane >> 4) * 4 + i;
        int gc = col0 + wc * 32 + nn * 16 + fr;
        out0[(size_t)gr * DM + gc] = acc[m][nn][i];
      }
}

// ---- attention: packed-fragment LDS (conflict-free), 32x32 MFMA, swapped
//      QK^T, in-register softmax, k-split-2, dbuf, counted vmcnt, and
//      SOFTWARE-PIPELINED PV: V staged one tile behind K; body is
//      QK(t) -> PV(t-1) -> exp/pack(t), so 20 MFMAs issue back-to-back and
//      exp2 retires under PV's MFMA execution. Packed P carried in registers.
__global__ __launch_bounds__(512, 4) void attn(const short* __restrict__ Qb,
                                               const short* __restrict__ KP,
                                               const short* __restrict__ VP,
                                               short* __restrict__ Ob) {
  __shared__ alignas(16) short kv[2][2][2][4096];  // [grp][K|V][buf][4096sh]
  const int bid = blockIdx.x;
  const int blk = (bid & 7) * 64 + (bid >> 3);  // XCD swizzle (512 % 8 == 0)
  const int qt = blk & 15;
  const int nh = blk >> 4;
  const int h = nh & (HN - 1);
  const int n = nh >> 3;
  const int wv = threadIdx.x >> 6, lane = threadIdx.x & 63;
  const int grp = wv >> 2, qs = wv & 3;
  const int l31 = lane & 31, hf = lane >> 5;
  const int q0 = qt * 128 + qs * 32;
  const float SC2 = 0.18033688011f;  // (1/8)*log2(e)

  bf16x8 qf[4];
  const short* qrow = Qb + (size_t)(n * TS + q0 + l31) * DM + h * HD;
#pragma unroll
  for (int ks = 0; ks < 4; ++ks) {
    bf16x8 t = *reinterpret_cast<const bf16x8*>(qrow + ks * 16 + hf * 8);
#pragma unroll
    for (int j = 0; j < 8; ++j) t[j] = f2bf(bf2f(t[j]) * SC2);
    qf[ks] = t;
  }

  bf16x8 ones;
#pragma unroll
  for (int i = 0; i < 8; ++i) ones[i] = (short)0x3F80;

  f32x16 o0, o1, osum, s0, s1;
#pragma unroll
  for (int r = 0; r < 16; ++r) {
    o0[r] = 0.f;
    o1[r] = 0.f;
    osum[r] = 0.f;
  }
  unsigned cw0[4][2], cw1[4][2];  // carried packed P (tile t-1)

  const int tbase = grp * 16;
  const size_t nhbase = (size_t)nh * 32 * 4096;  // shorts
  const int lb = lane * 16;                      // byte offset of lane's slot

#define STAGE_K(buf, t)                                                          \
  do {                                                                           \
    const short* kS = KP + nhbase + (size_t)(t) * 4096 + qs * 1024 + lane * 8;   \
    char* kb_ = (char*)&kv[grp][0][(buf)][0] + qs * 2048;                        \
    gload16(kS, kb_);                                                            \
    gload16(kS + 512, kb_ + 1024);                                               \
  } while (0)

#define STAGE_V(buf, t)                                                          \
  do {                                                                           \
    const short* vS = VP + nhbase + (size_t)(t) * 4096 + qs * 1024 + lane * 8;   \
    char* vb_ = (char*)&kv[grp][1][(buf)][0] + qs * 2048;                        \
    gload16(vS, vb_);                                                            \
    gload16(vS + 512, vb_ + 1024);                                               \
  } while (0)

#define QK_BODY(par)                                                             \
  do {                                                                           \
    const char* Kl = (const char*)&kv[grp][0][(par)][0];                         \
    _Pragma("unroll") for (int r = 0; r < 16; ++r) {                             \
      s0[r] = 0.f;                                                               \
      s1[r] = 0.f;                                                               \
    }                                                                            \
    __builtin_amdgcn_s_setprio(1);                                               \
    _Pragma("unroll") for (int ks = 0; ks < 4; ++ks) {                           \
      bf16x8 ka0 = *reinterpret_cast<const bf16x8*>(Kl + ks * 1024 + lb);        \
      bf16x8 ka1 = *reinterpret_cast<const bf16x8*>(Kl + (4 + ks) * 1024 + lb);  \
      s0 = MFMA32(ka0, qf[ks], s0);                                              \
      s1 = MFMA32(ka1, qf[ks], s1);                                              \
    }                                                                            \
    __builtin_amdgcn_s_setprio(0);                                               \
  } while (0)

#define PV_BODY(par)                                                             \
  do {                                                                           \
    const char* Vl = (const char*)&kv[grp][1][(par)][0];                         \
    __builtin_amdgcn_s_setprio(1);                                               \
    _Pragma("unroll") for (int ks = 0; ks < 4; ++ks) {                           \
      const int ce = (ks & 1) * 2, co = ce + 1;                                  \
      unsigned xa = (ks < 2) ? cw0[ce][0] : cw1[ce][0];                          \
      unsigned xb = (ks < 2) ? cw0[ce][1] : cw1[ce][1];                          \
      unsigned ya = (ks < 2) ? cw0[co][0] : cw1[co][0];                          \
      unsigned yb = (ks < 2) ? cw0[co][1] : cw1[co][1];                          \
      plane32swap(xa, ya);                                                       \
      plane32swap(xb, yb);                                                       \
      u32x4 pw;                                                                  \
      pw.x = xa;                                                                 \
      pw.y = xb;                                                                 \
      pw.z = ya;                                                                 \
      pw.w = yb;                                                                 \
      bf16x8 pa = *reinterpret_cast<bf16x8*>(&pw);                               \
      bf16x8 v0 = *reinterpret_cast<const bf16x8*>(Vl + ks * 1024 + lb);         \
      bf16x8 v1 = *reinterpret_cast<const bf16x8*>(Vl + (4 + ks) * 1024 + lb);   \
      o0 = MFMA32(pa, v0, o0);                                                   \
      o1 = MFMA32(pa, v1, o1);                                                   \
      osum = MFMA32(pa, ones, osum);                                             \
    }                                                                            \
    __builtin_amdgcn_s_setprio(0);                                               \
  } while (0)

#define EXPPACK                                                                  \
  do {                                                                           \
    _Pragma("unroll") for (int r = 0; r < 16; ++r) {                             \
      s0[r] = __builtin_amdgcn_exp2f(s0[r]);                                     \
      s1[r] = __builtin_amdgcn_exp2f(s1[r]);                                     \
    }                                                                            \
    _Pragma("unroll") for (int c = 0; c < 4; ++c) {                              \
      cw0[c][0] = cvtpk(s0[4 * c], s0[4 * c + 1]);                               \
      cw0[c][1] = cvtpk(s0[4 * c + 2], s0[4 * c + 3]);                           \
      cw1[c][0] = cvtpk(s1[4 * c], s1[4 * c + 1]);                               \
      cw1[c][1] = cvtpk(s1[4 * c + 2], s1[4 * c + 3]);                           \
    }                                                                            \
  } while (0)

  // pipeline fill: K(0)
  STAGE_K(0, tbase);
  // iter 0: QK(0), no PV
  STAGE_K(1, tbase + 1);
  STAGE_V(0, tbase);
  WAIT_VM(4);  // K(0) landed; K(1),V(0) in flight
  BAR();
  QK_BODY(0);
  EXPPACK;
  BAR();
  // steady: iters 1..14
  for (int j = 1; j < 15; ++j) {
    STAGE_K((j + 1) & 1, tbase + j + 1);
    STAGE_V(j & 1, tbase + j);
    WAIT_VM(4);  // K(j),V(j-1) landed; K(j+1),V(j) in flight
    BAR();
    QK_BODY(j & 1);
    PV_BODY((j + 1) & 1);  // == (j-1)&1
    EXPPACK;
    BAR();
  }
  // iter 15: last QK, stage only V(15)
  STAGE_V(1, tbase + 15);
  WAIT_VM(2);  // K(15),V(14) landed; V(15) in flight
  BAR();
  QK_BODY(1);
  PV_BODY(0);
  EXPPACK;
  BAR();
  // iter 16: drain — final PV
  WAIT_VM(0);
  BAR();
  PV_BODY(1);
  BAR();  // all PV reads done before LDS reuse in merge

#undef STAGE_K
#undef STAGE_V
#undef QK_BODY
#undef PV_BODY
#undef EXPPACK

  // merge group 1 -> group 0 via LDS (stride 49 f32 to avoid bank aliasing)
  float* sp = (float*)&kv[0][0][0][0];
  const int sbase = (qs * 64 + lane) * 49;
  if (grp == 1) {
#pragma unroll
    for (int r = 0; r < 16; ++r) {
      sp[sbase + r] = o0[r];
      sp[sbase + 16 + r] = o1[r];
      sp[sbase + 32 + r] = osum[r];
    }
  }
  __syncthreads();
  if (grp == 0) {
#pragma unroll
    for (int r = 0; r < 16; ++r) {
      o0[r] += sp[sbase + r];
      o1[r] += sp[sbase + 16 + r];
      osum[r] += sp[sbase + 32 + r];
    }
#pragma unroll
    for (int r = 0; r < 16; ++r) {
      int q = q0 + (r & 3) + 8 * (r >> 2) + 4 * hf;
      float is = 1.0f / osum[r];
      size_t base = (size_t)(n * TS + q) * DM + h * HD;
      Ob[base + l31] = f2bf(o0[r] * is);
      Ob[base + 32 + l31] = f2bf(o1[r] * is);
    }
  }
}

extern "C" void kernel_launch(void* const* d_in, const int* in_sizes, int n_in,
                              void* d_out, int out_size, void* d_ws, size_t ws_size,
                              hipStream_t stream) {
  (void)in_sizes; (void)n_in; (void)out_size; (void)ws_size;
  const float* Q = (const float*)d_in[0];
  const float* Wk = (const float*)d_in[1];
  const float* Wv = (const float*)d_in[2];
  const float* Wo = (const float*)d_in[3];

  const size_t QE = (size_t)NB * TS * DM;  // 4194304
  const size_t WE = (size_t)DM * DM;       // 262144
  short* ws = (short*)d_ws;
  short* Qb = ws;
  short* KP = Qb + QE;
  short* VP = KP + QE;
  short* Ao = VP + QE;
  short* Wkb = Ao + QE;
  short* Wvb = Wkb + WE;
  short* Wob = Wvb + WE;

  {
    int total4 = (int)((QE + 3 * WE) / 4);
    cast_all<<<total4 / 256, 256, 0, stream>>>(Q, Wk, Wv, Wo, Qb, Wkb);
  }
  {
    dim3 g(64, 8);
    gemm_kv<<<g, 256, 0, stream>>>(Qb, Wkb, Wvb, KP, VP);
  }
  attn<<<NB * HN * (TS / 128), 512, 0, stream>>>(Qb, KP, VP, Ao);
  {
    dim3 g(64, 8);
    gemm_o<<<g, 256, 0, stream>>>(Ao, Wob, (float*)d_out);
  }
}

// Round 14
// 78.596 us; speedup vs baseline: 2.2789x; 2.2789x over previous
//
#include <hip/hip_runtime.h>
#include <cstdint>
#include <cstddef>

#define NB 4
#define TS 2048
#define DM 512
#define HN 8
#define HD 64

typedef __attribute__((ext_vector_type(8))) short bf16x8;
typedef __attribute__((ext_vector_type(16))) float f32x16;
typedef __attribute__((ext_vector_type(4))) float f32x4;
typedef __attribute__((ext_vector_type(4))) short short4v;
typedef __attribute__((ext_vector_type(4))) unsigned u32x4;

static __device__ __forceinline__ short f2bf(float f) {
  unsigned u = __float_as_uint(f);
  unsigned r = (u + 0x7fffu + ((u >> 16) & 1u)) >> 16;  // RNE
  return (short)r;
}

static __device__ __forceinline__ float bf2f(short s) {
  return __uint_as_float(((unsigned)(unsigned short)s) << 16);
}

static __device__ __forceinline__ unsigned cvtpk(float lo, float hi) {
  unsigned r;
  asm("v_cvt_pk_bf16_f32 %0, %1, %2" : "=v"(r) : "v"(lo), "v"(hi));
  return r;
}

// x' = {x.lanes0-31, y.lanes0-31}; y' = {x.lanes32-63, y.lanes32-63}
static __device__ __forceinline__ void plane32swap(unsigned& x, unsigned& y) {
  asm volatile("v_permlane32_swap_b32 %0, %1" : "+v"(x), "+v"(y));
}

static __device__ __forceinline__ void gload16(const void* g, void* l) {
  __builtin_amdgcn_global_load_lds(
      (const __attribute__((address_space(1))) void*)g,
      (__attribute__((address_space(3))) void*)l, 16, 0, 0);
}

#define WAIT_VM(N) asm volatile("s_waitcnt vmcnt(" #N ")" ::: "memory")
#define BAR() __builtin_amdgcn_s_barrier()

#define MFMA16(a, b, c) __builtin_amdgcn_mfma_f32_16x16x32_bf16((a), (b), (c), 0, 0, 0)
#define MFMA32(a, b, c) __builtin_amdgcn_mfma_f32_32x32x16_bf16((a), (b), (c), 0, 0, 0)

// ---- fused cast: Q (fp32->bf16) + 3 weights; Wk gets +1.0 on the diagonal ----
__global__ __launch_bounds__(256) void cast_all(const float* __restrict__ Q,
                                                const float* __restrict__ Wk,
                                                const float* __restrict__ Wv,
                                                const float* __restrict__ Wo,
                                                short* __restrict__ Qb,
                                                short* __restrict__ Wb) {
  int i = blockIdx.x * 256 + threadIdx.x;
  const int Q4 = (NB * TS * DM) / 4;  // 1048576
  const float* src;
  short* dst;
  int off;
  int which = -1;
  if (i < Q4) {
    src = Q; dst = Qb; off = i;
  } else {
    int j = i - Q4;
    which = j >> 16;  // WE/4 = 65536
    off = j & 65535;
    src = which == 0 ? Wk : (which == 1 ? Wv : Wo);
    dst = Wb + ((size_t)which << 18);  // WE = 262144
  }
  float4 v = reinterpret_cast<const float4*>(src)[off];
  if (which == 0) {
    int e0 = off * 4;
    int row = e0 >> 9;
    int col0 = e0 & 511;
    if (row >= col0 && row < col0 + 4) {
      int c = row - col0;
      if (c == 0) v.x += 1.0f;
      else if (c == 1) v.y += 1.0f;
      else if (c == 2) v.z += 1.0f;
      else v.w += 1.0f;
    }
  }
  short4v o;
  o.x = f2bf(v.x);
  o.y = f2bf(v.y);
  o.z = f2bf(v.z);
  o.w = f2bf(v.w);
  reinterpret_cast<short4v*>(dst)[off] = o;
}

// ---- fused K+V projection writing FRAGMENT-PACKED outputs (R11 config) ----
// Kpack/Vpack unit: [(nh*32 + t)*8 + blk][lane 0..63][8 shorts]   (1KB blocks)
//   K: blk = H*4 + ks, lane = (k&31) + 32*((dd>>3)&1), j = dd&7   (H = k-half)
//   V: blk = D*4 + ks, lane = (dd&31) + 32*((k>>3)&1), j = k&7    (D = d-half)
__global__ __launch_bounds__(256) void gemm_kv(const short* __restrict__ Qb,
                                               const short* __restrict__ Wkb,
                                               const short* __restrict__ Wvb,
                                               short* __restrict__ KP,
                                               short* __restrict__ VP) {
  __shared__ alignas(16) short lA[2][128 * 32];  // Q tile
  __shared__ alignas(16) short lK[2][64 * 32];   // Wk tile
  __shared__ alignas(16) short lV[2][64 * 32];   // Wv tile
  const int row0 = blockIdx.x * 128;  // seq
  const int col0d = blockIdx.y * 64;  // d
  const int tid = threadIdx.x;
  const int lane = tid & 63;
  const int wave = tid >> 6;
  const int wr = wave >> 1, wc = wave & 1;
  const int fr = lane & 15, fk = (lane >> 4) * 8;
  const int g = lane >> 4;

  f32x4 kacc[2][4], vacc[4][2];
  const f32x4 z4 = {0.f, 0.f, 0.f, 0.f};
#pragma unroll
  for (int m = 0; m < 4; ++m)
#pragma unroll
    for (int nn = 0; nn < 2; ++nn) {
      kacc[nn][m] = z4;
      vacc[m][nn] = z4;
    }

  const int sr = tid >> 2;        // 0..63
  const int sc8 = (tid & 3) * 8;  // shorts

#define GSTAGE(buf, kt)                                                 \
  do {                                                                  \
    gload16(&Qb[(size_t)(row0 + sr) * DM + (kt) + sc8],                 \
            (char*)&lA[(buf)][0] + (size_t)tid * 16);                   \
    gload16(&Qb[(size_t)(row0 + 64 + sr) * DM + (kt) + sc8],            \
            (char*)&lA[(buf)][0] + 4096 + (size_t)tid * 16);            \
    gload16(&Wkb[(size_t)(col0d + sr) * DM + (kt) + sc8],               \
            (char*)&lK[(buf)][0] + (size_t)tid * 16);                   \
    gload16(&Wvb[(size_t)(col0d + sr) * DM + (kt) + sc8],               \
            (char*)&lV[(buf)][0] + (size_t)tid * 16);                   \
  } while (0)

  GSTAGE(0, 0);
  __syncthreads();
  int cur = 0;
  for (int kt = 0; kt < 16; ++kt) {
    if (kt < 15) GSTAGE(cur ^ 1, (kt + 1) * 32);
    bf16x8 af[4], wk[2], wv[2];
#pragma unroll
    for (int m = 0; m < 4; ++m)
      af[m] = *reinterpret_cast<const bf16x8*>(&lA[cur][(wr * 64 + m * 16 + fr) * 32 + fk]);
#pragma unroll
    for (int nn = 0; nn < 2; ++nn) {
      wk[nn] = *reinterpret_cast<const bf16x8*>(&lK[cur][(wc * 32 + nn * 16 + fr) * 32 + fk]);
      wv[nn] = *reinterpret_cast<const bf16x8*>(&lV[cur][(wc * 32 + nn * 16 + fr) * 32 + fk]);
    }
    __builtin_amdgcn_s_setprio(1);
#pragma unroll
    for (int m = 0; m < 4; ++m)
#pragma unroll
      for (int nn = 0; nn < 2; ++nn) {
        kacc[nn][m] = MFMA16(wk[nn], af[m], kacc[nn][m]);  // C[d][seq]
        vacc[m][nn] = MFMA16(af[m], wv[nn], vacc[m][nn]);  // C[seq][d]
      }
    __builtin_amdgcn_s_setprio(0);
    __syncthreads();
    cur ^= 1;
  }
#undef GSTAGE

  // K epilogue (C rows = d, cols = seq)
#pragma unroll
  for (int nn = 0; nn < 2; ++nn) {
#pragma unroll
    for (int m = 0; m < 4; ++m) {
      int d = col0d + wc * 32 + nn * 16 + g * 4;
      int kseq = row0 + wr * 64 + m * 16 + fr;
      int h = d >> 6, dd = d & 63;
      int n = kseq >> 11, kk = kseq & (TS - 1);
      int t = kk >> 6, H = (kk >> 5) & 1;
      int ks = (dd >> 4) & 3, hfd = (dd >> 3) & 1, jb = dd & 7;
      int slot = (kk & 31) + 32 * hfd;
      short4v pk;
#pragma unroll
      for (int i = 0; i < 4; ++i) pk[i] = f2bf(kacc[nn][m][i]);
      size_t addr = ((((size_t)(n * HN + h) * 32 + t) * 8 + H * 4 + ks) * 64 + slot) * 8 + jb;
      *reinterpret_cast<short4v*>(&KP[addr]) = pk;
    }
  }
  // V epilogue (C rows = seq, cols = d)
#pragma unroll
  for (int m = 0; m < 4; ++m) {
#pragma unroll
    for (int nn = 0; nn < 2; ++nn) {
      int kseq = row0 + wr * 64 + m * 16 + g * 4;
      int d = col0d + wc * 32 + nn * 16 + fr;
      int h = d >> 6, dd = d & 63;
      int n = kseq >> 11, kk = kseq & (TS - 1);
      int t = kk >> 6, hfk = (kk >> 3) & 1, jb = kk & 7;
      int ksV = (kk >> 4) & 3, D = (dd >> 5) & 1;
      int slot = (dd & 31) + 32 * hfk;
      short4v pv;
#pragma unroll
      for (int i = 0; i < 4; ++i) pv[i] = f2bf(vacc[m][nn][i]);
      size_t addr = ((((size_t)(n * HN + h) * 32 + t) * 8 + D * 4 + ksV) * 64 + slot) * 8 + jb;
      *reinterpret_cast<short4v*>(&VP[addr]) = pv;
    }
  }
}

// ---- O projection GEMM: 128x64 tile, BK=32, dbuf, fp32 out (R11 config) ----
__global__ __launch_bounds__(256) void gemm_o(const short* __restrict__ A,
                                              const short* __restrict__ W,
                                              float* __restrict__ out0) {
  __shared__ alignas(16) short lA[2][128 * 32];
  __shared__ alignas(16) short lB[2][64 * 32];
  const int row0 = blockIdx.x * 128;
  const int col0 = blockIdx.y * 64;
  const int tid = threadIdx.x;
  const int lane = tid & 63;
  const int wave = tid >> 6;
  const int wr = wave >> 1, wc = wave & 1;
  const int fr = lane & 15, fk = (lane >> 4) * 8;

  f32x4 acc[4][2];
  const f32x4 z4 = {0.f, 0.f, 0.f, 0.f};
#pragma unroll
  for (int m = 0; m < 4; ++m)
#pragma unroll
    for (int nn = 0; nn < 2; ++nn) acc[m][nn] = z4;

  const int sr = tid >> 2;
  const int sc8 = (tid & 3) * 8;

#define GSTAGE(buf, kt)                                                \
  do {                                                                 \
    gload16(&A[(size_t)(row0 + sr) * DM + (kt) + sc8],                 \
            (char*)&lA[(buf)][0] + (size_t)tid * 16);                  \
    gload16(&A[(size_t)(row0 + 64 + sr) * DM + (kt) + sc8],            \
            (char*)&lA[(buf)][0] + 4096 + (size_t)tid * 16);           \
    gload16(&W[(size_t)(col0 + sr) * DM + (kt) + sc8],                 \
            (char*)&lB[(buf)][0] + (size_t)tid * 16);                  \
  } while (0)

  GSTAGE(0, 0);
  __syncthreads();
  int cur = 0;
  for (int kt = 0; kt < 16; ++kt) {
    if (kt < 15) GSTAGE(cur ^ 1, (kt + 1) * 32);
    bf16x8 af[4], bfr[2];
#pragma unroll
    for (int m = 0; m < 4; ++m)
      af[m] = *reinterpret_cast<const bf16x8*>(&lA[cur][(wr * 64 + m * 16 + fr) * 32 + fk]);
#pragma unroll
    for (int nn = 0; nn < 2; ++nn)
      bfr[nn] = *reinterpret_cast<const bf16x8*>(&lB[cur][(wc * 32 + nn * 16 + fr) * 32 + fk]);
    __builtin_amdgcn_s_setprio(1);
#pragma unroll
    for (int m = 0; m < 4; ++m)
#pragma unroll
      for (int nn = 0; nn < 2; ++nn) acc[m][nn] = MFMA16(af[m], bfr[nn], acc[m][nn]);
    __builtin_amdgcn_s_setprio(0);
    __syncthreads();
    cur ^= 1;
  }
#undef GSTAGE

#pragma unroll
  for (int m = 0; m < 4; ++m)
#pragma unroll
    for (int nn = 0; nn < 2; ++nn)
#pragma unroll
      for (int i = 0; i < 4; ++i) {
        int gr = row0 + wr * 64 + m * 16 + (lane >> 4) * 4 + i;
        int gc = col0 + wc * 32 + nn * 16 + fr;
        out0[(size_t)gr * DM + gc] = acc[m][nn][i];
      }
}

// ---- attention: packed-fragment LDS, 32x32 MFMA, swapped QK^T, in-register
//      softmax, k-split-2, PIPELINED: body = PV(t-1) -> QK(t) -> EXPPACK(t).
//      Row sums on VALU (rs[4] per lane, q = l31) instead of ones-MFMA:
//      -4 MFMA/tile and -20 registers vs R13 (which spilled at ~145 live).
//      Peak live now ~110 < 128 cap of __launch_bounds__(512,4).
__global__ __launch_bounds__(512, 4) void attn(const short* __restrict__ Qb,
                                               const short* __restrict__ KP,
                                               const short* __restrict__ VP,
                                               short* __restrict__ Ob) {
  __shared__ alignas(16) short kv[2][2][2][4096];  // [grp][K|V][buf][4096sh]
  const int bid = blockIdx.x;
  const int blk = (bid & 7) * 64 + (bid >> 3);  // XCD swizzle (512 % 8 == 0)
  const int qt = blk & 15;
  const int nh = blk >> 4;
  const int h = nh & (HN - 1);
  const int n = nh >> 3;
  const int wv = threadIdx.x >> 6, lane = threadIdx.x & 63;
  const int grp = wv >> 2, qs = wv & 3;
  const int l31 = lane & 31, hf = lane >> 5;
  const int q0 = qt * 128 + qs * 32;
  const float SC2 = 0.18033688011f;  // (1/8)*log2(e)

  bf16x8 qf[4];
  const short* qrow = Qb + (size_t)(n * TS + q0 + l31) * DM + h * HD;
#pragma unroll
  for (int ks = 0; ks < 4; ++ks) {
    bf16x8 t = *reinterpret_cast<const bf16x8*>(qrow + ks * 16 + hf * 8);
#pragma unroll
    for (int j = 0; j < 8; ++j) t[j] = f2bf(bf2f(t[j]) * SC2);
    qf[ks] = t;
  }

  f32x16 o0, o1, s0, s1;
#pragma unroll
  for (int r = 0; r < 16; ++r) {
    o0[r] = 0.f;
    o1[r] = 0.f;
  }
  float rs[4] = {0.f, 0.f, 0.f, 0.f};   // per-lane row-sum partials (q = l31)
  unsigned cw0[4][2], cw1[4][2];        // carried packed P (tile t-1)

  const int tbase = grp * 16;
  const size_t nhbase = (size_t)nh * 32 * 4096;  // shorts
  const int lb = lane * 16;                      // byte offset of lane's slot

#define STAGE_K(buf, t)                                                          \
  do {                                                                           \
    const short* kS = KP + nhbase + (size_t)(t) * 4096 + qs * 1024 + lane * 8;   \
    char* kb_ = (char*)&kv[grp][0][(buf)][0] + qs * 2048;                        \
    gload16(kS, kb_);                                                            \
    gload16(kS + 512, kb_ + 1024);                                               \
  } while (0)

#define STAGE_V(buf, t)                                                          \
  do {                                                                           \
    const short* vS = VP + nhbase + (size_t)(t) * 4096 + qs * 1024 + lane * 8;   \
    char* vb_ = (char*)&kv[grp][1][(buf)][0] + qs * 2048;                        \
    gload16(vS, vb_);                                                            \
    gload16(vS + 512, vb_ + 1024);                                               \
  } while (0)

#define QK_BODY(par)                                                             \
  do {                                                                           \
    const char* Kl = (const char*)&kv[grp][0][(par)][0];                         \
    _Pragma("unroll") for (int r = 0; r < 16; ++r) {                             \
      s0[r] = 0.f;                                                               \
      s1[r] = 0.f;                                                               \
    }                                                                            \
    __builtin_amdgcn_s_setprio(1);                                               \
    _Pragma("unroll") for (int ks = 0; ks < 4; ++ks) {                           \
      bf16x8 ka0 = *reinterpret_cast<const bf16x8*>(Kl + ks * 1024 + lb);        \
      bf16x8 ka1 = *reinterpret_cast<const bf16x8*>(Kl + (4 + ks) * 1024 + lb);  \
      s0 = MFMA32(ka0, qf[ks], s0);                                              \
      s1 = MFMA32(ka1, qf[ks], s1);                                              \
    }                                                                            \
    __builtin_amdgcn_s_setprio(0);                                               \
  } while (0)

#define PV_BODY(par)                                                             \
  do {                                                                           \
    const char* Vl = (const char*)&kv[grp][1][(par)][0];                         \
    __builtin_amdgcn_s_setprio(1);                                               \
    _Pragma("unroll") for (int ks = 0; ks < 4; ++ks) {                           \
      const int ce = (ks & 1) * 2, co = ce + 1;                                  \
      unsigned xa = (ks < 2) ? cw0[ce][0] : cw1[ce][0];                          \
      unsigned xb = (ks < 2) ? cw0[ce][1] : cw1[ce][1];                          \
      unsigned ya = (ks < 2) ? cw0[co][0] : cw1[co][0];                          \
      unsigned yb = (ks < 2) ? cw0[co][1] : cw1[co][1];                          \
      plane32swap(xa, ya);                                                       \
      plane32swap(xb, yb);                                                       \
      u32x4 pw;                                                                  \
      pw.x = xa;                                                                 \
      pw.y = xb;                                                                 \
      pw.z = ya;                                                                 \
      pw.w = yb;                                                                 \
      bf16x8 pa = *reinterpret_cast<bf16x8*>(&pw);                               \
      bf16x8 v0 = *reinterpret_cast<const bf16x8*>(Vl + ks * 1024 + lb);         \
      bf16x8 v1 = *reinterpret_cast<const bf16x8*>(Vl + (4 + ks) * 1024 + lb);   \
      o0 = MFMA32(pa, v0, o0);                                                   \
      o1 = MFMA32(pa, v1, o1);                                                   \
    }                                                                            \
    __builtin_amdgcn_s_setprio(0);                                               \
  } while (0)

#define EXPPACK                                                                  \
  do {                                                                           \
    _Pragma("unroll") for (int r = 0; r < 16; ++r) {                             \
      s0[r] = __builtin_amdgcn_exp2f(s0[r]);                                     \
      s1[r] = __builtin_amdgcn_exp2f(s1[r]);                                     \
    }                                                                            \
    _Pragma("unroll") for (int r = 0; r < 16; ++r) rs[r & 3] += s0[r] + s1[r];   \
    _Pragma("unroll") for (int c = 0; c < 4; ++c) {                              \
      cw0[c][0] = cvtpk(s0[4 * c], s0[4 * c + 1]);                               \
      cw0[c][1] = cvtpk(s0[4 * c + 2], s0[4 * c + 3]);                           \
      cw1[c][0] = cvtpk(s1[4 * c], s1[4 * c + 1]);                               \
      cw1[c][1] = cvtpk(s1[4 * c + 2], s1[4 * c + 3]);                           \
    }                                                                            \
  } while (0)

  // pipeline fill
  STAGE_K(0, tbase);
  STAGE_K(1, tbase + 1);
  STAGE_V(0, tbase);
  WAIT_VM(4);  // K(0) landed; K(1),V(0) in flight
  BAR();
  QK_BODY(0);
  EXPPACK;
  BAR();
  // steady: iters 1..14, body = PV(j-1) -> QK(j) -> EXPPACK(j)
  for (int j = 1; j < 15; ++j) {
    STAGE_K((j + 1) & 1, tbase + j + 1);
    STAGE_V(j & 1, tbase + j);
    WAIT_VM(4);  // K(j),V(j-1) landed; K(j+1),V(j) in flight
    BAR();
    PV_BODY((j + 1) & 1);  // == (j-1)&1
    QK_BODY(j & 1);
    EXPPACK;
    BAR();
  }
  // iter 15: last QK, stage only V(15)
  STAGE_V(1, tbase + 15);
  WAIT_VM(2);  // K(15),V(14) landed; V(15) in flight
  BAR();
  PV_BODY(0);  // V(14)
  QK_BODY(1);  // K(15)
  EXPPACK;
  // drain: final PV on V(15)
  WAIT_VM(0);
  BAR();
  PV_BODY(1);
  BAR();  // all LDS reads done before merge reuses the buffer

#undef STAGE_K
#undef STAGE_V
#undef QK_BODY
#undef PV_BODY
#undef EXPPACK

  // finalize per-lane row sum: lane l31 holds sum for q = q0 + l31 (per hf half)
  float rst = (rs[0] + rs[1]) + (rs[2] + rs[3]);
  rst += __shfl_xor(rst, 32);

  // merge group 1 -> group 0 via LDS (stride 33 f32)
  float* sp = (float*)&kv[0][0][0][0];
  const int sbase = (qs * 64 + lane) * 33;
  if (grp == 1) {
#pragma unroll
    for (int r = 0; r < 16; ++r) {
      sp[sbase + r] = o0[r];
      sp[sbase + 16 + r] = o1[r];
    }
    sp[sbase + 32] = rst;
  }
  __syncthreads();
  if (grp == 0) {
#pragma unroll
    for (int r = 0; r < 16; ++r) {
      o0[r] += sp[sbase + r];
      o1[r] += sp[sbase + 16 + r];
    }
    rst += sp[sbase + 32];
    float invv = 1.0f / rst;  // inv row-sum for q = q0 + l31
#pragma unroll
    for (int r = 0; r < 16; ++r) {
      int crow = (r & 3) + 8 * (r >> 2) + 4 * hf;
      float is = __shfl(invv, crow);  // fetch inv for this row from lane crow
      int q = q0 + crow;
      size_t base = (size_t)(n * TS + q) * DM + h * HD;
      Ob[base + l31] = f2bf(o0[r] * is);
      Ob[base + 32 + l31] = f2bf(o1[r] * is);
    }
  }
}

extern "C" void kernel_launch(void* const* d_in, const int* in_sizes, int n_in,
                              void* d_out, int out_size, void* d_ws, size_t ws_size,
                              hipStream_t stream) {
  (void)in_sizes; (void)n_in; (void)out_size; (void)ws_size;
  const float* Q = (const float*)d_in[0];
  const float* Wk = (const float*)d_in[1];
  const float* Wv = (const float*)d_in[2];
  const float* Wo = (const float*)d_in[3];

  const size_t QE = (size_t)NB * TS * DM;  // 4194304
  const size_t WE = (size_t)DM * DM;       // 262144
  short* ws = (short*)d_ws;
  short* Qb = ws;
  short* KP = Qb + QE;
  short* VP = KP + QE;
  short* Ao = VP + QE;
  short* Wkb = Ao + QE;
  short* Wvb = Wkb + WE;
  short* Wob = Wvb + WE;

  {
    int total4 = (int)((QE + 3 * WE) / 4);
    cast_all<<<total4 / 256, 256, 0, stream>>>(Q, Wk, Wv, Wo, Qb, Wkb);
  }
  {
    dim3 g(64, 8);
    gemm_kv<<<g, 256, 0, stream>>>(Qb, Wkb, Wvb, KP, VP);
  }
  attn<<<NB * HN * (TS / 128), 512, 0, stream>>>(Qb, KP, VP, Ao);
  {
    dim3 g(64, 8);
    gemm_o<<<g, 256, 0, stream>>>(Ao, Wob, (float*)d_out);
  }
}